// Round 6
// baseline (235.965 us; speedup 1.0000x reference)
//
#include <hip/hip_runtime.h>
#include <cstdint>
#include <math.h>

#define B2v 4
#define Cc  128
#define Hh  64
#define Ww  256
#define Gg  8
#define Pp  4
#define HW  (Hh*Ww)      // 16384
#define CHW (Cc*HW)      // 2097152
#define PIT 136          // LDS tile pitch in bf16 elems (272 B rows, 16B-aligned)

typedef float f32x4 __attribute__((ext_vector_type(4)));
typedef float f32x2 __attribute__((ext_vector_type(2)));
typedef short s16x8 __attribute__((ext_vector_type(8)));
typedef short s16x4 __attribute__((ext_vector_type(4)));
typedef unsigned u32x2 __attribute__((ext_vector_type(2)));
typedef unsigned u32x4 __attribute__((ext_vector_type(4)));

__device__ __forceinline__ short f2bf(float x) {
    union { float f; unsigned u; } a; a.f = x;
    unsigned r = a.u + 0x7fffu + ((a.u >> 16) & 1u);   // RNE
    return (short)(r >> 16);
}
__device__ __forceinline__ float bf2f(short s) {
    union { unsigned u; float f; } a; a.u = ((unsigned)(unsigned short)s) << 16;
    return a.f;
}
// pack two f32 -> dword of two bf16 (truncation, 1 inst)
__device__ __forceinline__ unsigned pack2_bf(float f0, float f1) {
    union { float f; unsigned u; } a, b; a.f = f0; b.f = f1;
    return __builtin_amdgcn_perm(b.u, a.u, 0x07060302);  // lo=hi16(f0), hi=hi16(f1)
}
// packed dword (2 bf16) -> float2 {lo, hi}
__device__ __forceinline__ f32x2 bf2_lohi(unsigned d) {
    union { unsigned u; float f; } lo, hi;
    lo.u = d << 16; hi.u = d & 0xffff0000u;
    return (f32x2){lo.f, hi.f};
}

// ---------------------------------------------------------------------------
// Kernel 0: weights f32 -> bf16 (RNE).
// [0,16384) wv | [16384,32768) wq=[woc;wog;wa] | [32768,49152) wo
// [49152,81920) w1 | [81920,114688) w2 ; bq[128]=[boc;bog;ba] f32
// ---------------------------------------------------------------------------
__global__ __launch_bounds__(256) void prep_kernel(
    const float* __restrict__ wv, const float* __restrict__ woc,
    const float* __restrict__ wog, const float* __restrict__ wa,
    const float* __restrict__ wo, const float* __restrict__ w1,
    const float* __restrict__ w2,
    const float* __restrict__ boc, const float* __restrict__ bog,
    const float* __restrict__ ba,
    short* __restrict__ wbf, float* __restrict__ bq)
{
    int i = blockIdx.x * 256 + threadIdx.x;
    if (i < 16384) wbf[i] = f2bf(wv[i]);
    else if (i < 32768) {
        int j = i - 16384; int r = j >> 7, c = j & 127;
        float v = (r < 32) ? woc[r * 128 + c] : (r < 64) ? wog[(r - 32) * 128 + c]
                                              : wa[(r - 64) * 128 + c];
        wbf[i] = f2bf(v);
    }
    else if (i < 49152)  wbf[i] = f2bf(wo[i - 32768]);
    else if (i < 81920)  wbf[i] = f2bf(w1[i - 49152]);
    else if (i < 114688) wbf[i] = f2bf(w2[i - 81920]);
    else if (i < 114816) {
        int r = i - 114688;
        bq[r] = (r < 32) ? boc[r] : (r < 64) ? bog[r - 32] : ba[r - 64];
    }
}

// ---------------------------------------------------------------------------
// Mega kernel v2: block = one output row (b,h), 512 threads (8 waves).
// P0 stage ctx->buf1 + q->buf2 (+cap/gap prefetch) | P1 value&proj GEMMs ->
// regs | P2 write value->buf1, proj->buf2 | P3 softmax/keypoints (regs) |
// P4 sampling -> agg->buf2 | P5 wo GEMM + residual -> buf1 | P6 LN |
// P7 FFN (2 passes via buf2) | P8 store.
// ---------------------------------------------------------------------------
__global__ __launch_bounds__(512, 2) void mega_kernel(
    const float* __restrict__ mlq, const float* __restrict__ mrq,
    const float* __restrict__ fl,  const float* __restrict__ fr,
    const float* __restrict__ nl,  const float* __restrict__ nr,
    const float* __restrict__ gml, const float* __restrict__ gmr,
    const float* __restrict__ cap, const float* __restrict__ gap,
    const short* __restrict__ wbf, const float* __restrict__ bq,
    const float* __restrict__ bv,
    const float* __restrict__ wn,  const float* __restrict__ bn,
    const float* __restrict__ bo,
    const float* __restrict__ lnw, const float* __restrict__ lnb,
    const float* __restrict__ b1,  const float* __restrict__ b2,
    float* __restrict__ out_ml, float* __restrict__ out_mr,
    float* __restrict__ ckp_out, float* __restrict__ gkp_out)
{
    __shared__ short buf1[256 * PIT];   // ctx -> value -> x/xn
    __shared__ short buf2[256 * PIT];   // q -> proj -> agg -> ffn hidden
    __shared__ float sgeo[3 * 256];
    __shared__ float swn4[128 * 4];
    __shared__ float redS[512], redQ[512];
    __shared__ float smu[256], srs[256];

    const short* wv_bf = wbf;
    const short* wq_bf = wbf + 16384;
    const short* wo_bf = wbf + 32768;
    const short* w1_bf = wbf + 49152;
    const short* w2_bf = wbf + 81920;

    const int t    = threadIdx.x;
    const int lane = t & 63;
    const int ww   = t >> 6;          // wave 0..7
    const int lm   = lane & 15;
    const int lq   = lane >> 4;
    const int h = blockIdx.x, b = blockIdx.y;
    const int hWw = h * Ww;
    const int px   = t & 255;
    const int half = t >> 8;          // 0/1

    const float* ctx = (b < 2) ? fr + (size_t)b * CHW : fl + (size_t)(b - 2) * CHW;
    const float* q   = (b < 2) ? mlq + (size_t)b * CHW : mrq + (size_t)(b - 2) * CHW;
    const float* geo = (b < 2) ? nr + (size_t)b * 3 * HW : nl + (size_t)(b - 2) * 3 * HW;
    const float* msk = (b < 2) ? gml + (size_t)b * HW : gmr + (size_t)(b - 2) * HW;
    float* outp = (b < 2) ? out_ml + (size_t)b * CHW : out_mr + (size_t)(b - 2) * CHW;

    // ---- P0a: prefetch anchors into registers (hidden behind staging) ----
    float capr[16], gapr[16];
#pragma unroll
    for (int gi = 0; gi < 4; gi++) {
        const int g = half * 4 + gi;
#pragma unroll
        for (int p = 0; p < 4; p++) {
            size_t kidx = ((((size_t)b * Gg + g) * Pp + p) * Hh + h) * Ww + px;
            capr[gi * 4 + p] = cap[kidx];
            gapr[gi * 4 + p] = gap[kidx];
        }
    }

    // ---- P0b: small constants ----
    for (int i = t; i < 768; i += 512) sgeo[i] = geo[(size_t)(i >> 8) * HW + hWw + (i & 255)];
    if (t < 128) {
        swn4[t * 4 + 0] = wn[t * 3 + 0];
        swn4[t * 4 + 1] = wn[t * 3 + 1];
        swn4[t * 4 + 2] = wn[t * 3 + 2];
        swn4[t * 4 + 3] = bn[t];
    }

    // ---- P0c: stage ctx->buf1 AND q->buf2 (interleaved, bf16 trunc) ----
    {
        const int c0 = ww * 16;
#pragma unroll
        for (int sub = 0; sub < 4; sub++) {
            const int p = sub * 64 + lane;
            const size_t base = (size_t)c0 * HW + hWw + p;
#pragma unroll
            for (int k = 0; k < 8; k++) {
                float c0f = ctx[base + (size_t)(2 * k) * HW];
                float c1f = ctx[base + (size_t)(2 * k + 1) * HW];
                float q0f = q[base + (size_t)(2 * k) * HW];
                float q1f = q[base + (size_t)(2 * k + 1) * HW];
                *(unsigned*)(&buf1[p * PIT + c0 + 2 * k]) = pack2_bf(c0f, c1f);
                *(unsigned*)(&buf2[p * PIT + c0 + 2 * k]) = pack2_bf(q0f, q1f);
            }
        }
    }
    __syncthreads();

    // ---- P1: value = wv@ctx and proj = wq@q, both -> registers ----
    f32x4 accV[16], accP[16];
#pragma unroll
    for (int nt = 0; nt < 16; nt++) {
        accV[nt] = (f32x4){0.f, 0.f, 0.f, 0.f};
        accP[nt] = (f32x4){0.f, 0.f, 0.f, 0.f};
    }
#pragma unroll
    for (int kk = 0; kk < 4; kk++) {
        s16x8 aV = *(const s16x8*)(wv_bf + (size_t)(ww * 16 + lm) * 128 + kk * 32 + lq * 8);
        s16x8 aP = *(const s16x8*)(wq_bf + (size_t)(ww * 16 + lm) * 128 + kk * 32 + lq * 8);
#pragma unroll
        for (int nt = 0; nt < 16; nt++) {
            s16x8 bV = *(const s16x8*)(&buf1[(nt * 16 + lm) * PIT + kk * 32 + lq * 8]);
            s16x8 bP = *(const s16x8*)(&buf2[(nt * 16 + lm) * PIT + kk * 32 + lq * 8]);
            accV[nt] = __builtin_amdgcn_mfma_f32_16x16x32_bf16(aV, bV, accV[nt], 0, 0, 0);
            accP[nt] = __builtin_amdgcn_mfma_f32_16x16x32_bf16(aP, bP, accP[nt], 0, 0, 0);
        }
    }
    __syncthreads();

    // ---- P2: value+bv -> buf1, proj+bq -> buf2 (trunc pair packs) ----
    {
        const int ob = ww * 16 + lq * 4;
        float bvv[4], bqv[4];
#pragma unroll
        for (int r = 0; r < 4; r++) { bvv[r] = bv[ob + r]; bqv[r] = bq[ob + r]; }
#pragma unroll
        for (int nt = 0; nt < 16; nt++) {
            const int wg = nt * 16 + lm;
            u32x2 pv, pp;
            pv[0] = pack2_bf(accV[nt][0] + bvv[0], accV[nt][1] + bvv[1]);
            pv[1] = pack2_bf(accV[nt][2] + bvv[2], accV[nt][3] + bvv[3]);
            pp[0] = pack2_bf(accP[nt][0] + bqv[0], accP[nt][1] + bqv[1]);
            pp[1] = pack2_bf(accP[nt][2] + bqv[2], accP[nt][3] + bqv[3]);
            *(u32x2*)(&buf1[wg * PIT + ob]) = pv;
            *(u32x2*)(&buf2[wg * PIT + ob]) = pp;
        }
    }
    __syncthreads();

    // ---- P3: softmax + keypoints (registers), ckp/gkp stores ----
    float attnr[4][8], kpr[4][8];
#pragma unroll
    for (int gi = 0; gi < 4; gi++) {
        const int g = half * 4 + gi;
        s16x8 lg = *(const s16x8*)(&buf2[px * PIT + 64 + g * 8]);
        float L[8], m = -1e30f;
#pragma unroll
        for (int j = 0; j < 8; j++) { L[j] = bf2f(lg[j]); m = fmaxf(m, L[j]); }
        float s = 0.f;
#pragma unroll
        for (int j = 0; j < 8; j++) { L[j] = __expf(L[j] - m); s += L[j]; }
        float inv = 1.f / s;
#pragma unroll
        for (int j = 0; j < 8; j++) attnr[gi][j] = L[j] * inv;
#pragma unroll
        for (int p = 0; p < 4; p++) {
            size_t kidx = ((((size_t)b * Gg + g) * Pp + p) * Hh + h) * Ww + px;
            float oc = bf2f(buf2[px * PIT + g * 4 + p]);
            float og = bf2f(buf2[px * PIT + 32 + g * 4 + p]);
            float ck = fminf(fmaxf(capr[gi * 4 + p] * 255.0f + oc, 0.f), 255.f);
            float gk = fminf(fmaxf(gapr[gi * 4 + p] * 255.0f + og, 0.f), 255.f);
            ckp_out[kidx] = ck;
            gkp_out[kidx] = gk;
            kpr[gi][p] = ck;
            kpr[gi][4 + p] = gk;
        }
    }
    __syncthreads();   // proj consumed; buf2 reusable

    // ---- P4: deformable sampling -> agg -> buf2 [px][ch] ----
#pragma unroll
    for (int gi = 0; gi < 4; gi++) {
        const int g = half * 4 + gi;
        f32x2 a2[8];
#pragma unroll
        for (int k = 0; k < 8; k++) a2[k] = (f32x2){0.f, 0.f};
        // ctx points: gather value pairs from buf1, packed fma
#pragma unroll
        for (int j = 0; j < 4; j++) {
            float x = kpr[gi][j];
            int i0 = (int)floorf(x);
            int i1 = min(i0 + 1, Ww - 1);
            float tt = x - (float)i0;
            float w0 = attnr[gi][j] * (1.f - tt);
            float w1v = attnr[gi][j] * tt;
            f32x2 c0 = (f32x2){w0, w0}, c1 = (f32x2){w1v, w1v};
            const u32x4* p0 = (const u32x4*)(&buf1[i0 * PIT + g * 16]);
            const u32x4* p1 = (const u32x4*)(&buf1[i1 * PIT + g * 16]);
            u32x4 d0a = p0[0], d0b = p0[1];
            u32x4 d1a = p1[0], d1b = p1[1];
#pragma unroll
            for (int k = 0; k < 4; k++) {
                a2[k]     += c0 * bf2_lohi(d0a[k]) + c1 * bf2_lohi(d1a[k]);
                a2[4 + k] += c0 * bf2_lohi(d0b[k]) + c1 * bf2_lohi(d1b[k]);
            }
        }
        // geo points via linearity: wn @ sample(geo) + bn * sum(attn_geo)
        {
            float gs0 = 0.f, gs1 = 0.f, gs2 = 0.f, as = 0.f;
#pragma unroll
            for (int j = 4; j < 8; j++) {
                float x = kpr[gi][j];
                int i0 = (int)floorf(x);
                int i1 = min(i0 + 1, Ww - 1);
                float tt = x - (float)i0;
                float c0 = attnr[gi][j] * (1.f - tt);
                float c1 = attnr[gi][j] * tt;
                gs0 += c0 * sgeo[i0] + c1 * sgeo[i1];
                gs1 += c0 * sgeo[256 + i0] + c1 * sgeo[256 + i1];
                gs2 += c0 * sgeo[512 + i0] + c1 * sgeo[512 + i1];
                as  += attnr[gi][j];
            }
#pragma unroll
            for (int k = 0; k < 8; k++) {
                const float* wa4 = &swn4[(g * 16 + 2 * k) * 4];
                const float* wb4 = wa4 + 4;
                a2[k].x += wa4[0] * gs0 + wa4[1] * gs1 + wa4[2] * gs2 + wa4[3] * as;
                a2[k].y += wb4[0] * gs0 + wb4[1] * gs1 + wb4[2] * gs2 + wb4[3] * as;
            }
        }
        u32x4 pk0;
#pragma unroll
        for (int k = 0; k < 4; k++) pk0[k] = pack2_bf(a2[k].x, a2[k].y);
        u32x4 pk1;
#pragma unroll
        for (int k = 0; k < 4; k++) pk1[k] = pack2_bf(a2[4 + k].x, a2[4 + k].y);
        *(u32x4*)(&buf2[px * PIT + g * 16])     = pk0;
        *(u32x4*)(&buf2[px * PIT + g * 16 + 8]) = pk1;
    }
    __syncthreads();

    // ---- P5: upd = wo @ agg ; x = q + (upd+bo)*mask -> buf1 ----
    {
        f32x4 acc1[16];
#pragma unroll
        for (int nt = 0; nt < 16; nt++) acc1[nt] = (f32x4){0.f, 0.f, 0.f, 0.f};
#pragma unroll
        for (int kk = 0; kk < 4; kk++) {
            s16x8 a = *(const s16x8*)(wo_bf + (size_t)(ww * 16 + lm) * 128 + kk * 32 + lq * 8);
#pragma unroll
            for (int nt = 0; nt < 16; nt++) {
                s16x8 bfv = *(const s16x8*)(&buf2[(nt * 16 + lm) * PIT + kk * 32 + lq * 8]);
                acc1[nt] = __builtin_amdgcn_mfma_f32_16x16x32_bf16(a, bfv, acc1[nt], 0, 0, 0);
            }
        }
        // buf1 (value) is dead after P4's barrier; write x without extra barrier
        const int ob = ww * 16 + lq * 4;
        float bias[4];
#pragma unroll
        for (int r = 0; r < 4; r++) bias[r] = bo[ob + r];
#pragma unroll
        for (int nt = 0; nt < 16; nt++) {
            const int wg = nt * 16 + lm;
            float mval = msk[hWw + wg];
            float x0 = q[(size_t)(ob + 0) * HW + hWw + wg] + (acc1[nt][0] + bias[0]) * mval;
            float x1 = q[(size_t)(ob + 1) * HW + hWw + wg] + (acc1[nt][1] + bias[1]) * mval;
            float x2 = q[(size_t)(ob + 2) * HW + hWw + wg] + (acc1[nt][2] + bias[2]) * mval;
            float x3 = q[(size_t)(ob + 3) * HW + hWw + wg] + (acc1[nt][3] + bias[3]) * mval;
            u32x2 pk;
            pk[0] = pack2_bf(x0, x1);
            pk[1] = pack2_bf(x2, x3);
            *(u32x2*)(&buf1[wg * PIT + ob]) = pk;
        }
    }
    __syncthreads();

    // ---- P6: LayerNorm over channels (in buf1, bf16) ----
    {
        float ls = 0.f, lsq = 0.f;
#pragma unroll
        for (int c4 = 0; c4 < 16; c4++) {
            unsigned d = *(const unsigned*)(&buf1[px * PIT + half * 64 + c4 * 4]);
            unsigned d2 = *(const unsigned*)(&buf1[px * PIT + half * 64 + c4 * 4 + 2]);
            f32x2 v = bf2_lohi(d), v2 = bf2_lohi(d2);
            ls += v.x + v.y + v2.x + v2.y;
            lsq += v.x * v.x + v.y * v.y + v2.x * v2.x + v2.y * v2.y;
        }
        redS[t] = ls; redQ[t] = lsq;
        __syncthreads();
        if (t < 256) {
            float s  = redS[t] + redS[t + 256];
            float qq = redQ[t] + redQ[t + 256];
            float mu = s * (1.f / 128.f);
            float var = qq * (1.f / 128.f) - mu * mu;
            smu[t] = mu;
            srs[t] = rsqrtf(var + 1e-5f);
        }
        __syncthreads();
        const float mu = smu[px], rs = srs[px];
#pragma unroll
        for (int c8 = 0; c8 < 8; c8++) {
            const int c = half * 64 + c8 * 8;
            u32x4 d = *(const u32x4*)(&buf1[px * PIT + c]);
            u32x4 o;
#pragma unroll
            for (int k = 0; k < 4; k++) {
                f32x2 v = bf2_lohi(d[k]);
                float y0 = (v.x - mu) * rs * lnw[c + 2 * k] + lnb[c + 2 * k];
                float y1 = (v.y - mu) * rs * lnw[c + 2 * k + 1] + lnb[c + 2 * k + 1];
                o[k] = pack2_bf(y0, y1);
            }
            *(u32x4*)(&buf1[px * PIT + c]) = o;
        }
    }
    __syncthreads();

    // ---- P7: FFN, two 128-col hidden passes through buf2 ----
    f32x4 acc3[16];
#pragma unroll
    for (int nt = 0; nt < 16; nt++) acc3[nt] = (f32x4){0.f, 0.f, 0.f, 0.f};

    for (int jc = 0; jc < 2; jc++) {
        f32x4 acc2[16];
#pragma unroll
        for (int nt = 0; nt < 16; nt++) acc2[nt] = (f32x4){0.f, 0.f, 0.f, 0.f};
#pragma unroll
        for (int kk = 0; kk < 4; kk++) {
            s16x8 a = *(const s16x8*)(w1_bf + (size_t)(jc * 128 + ww * 16 + lm) * 128 + kk * 32 + lq * 8);
#pragma unroll
            for (int nt = 0; nt < 16; nt++) {
                s16x8 bfv = *(const s16x8*)(&buf1[(nt * 16 + lm) * PIT + kk * 32 + lq * 8]);
                acc2[nt] = __builtin_amdgcn_mfma_f32_16x16x32_bf16(a, bfv, acc2[nt], 0, 0, 0);
            }
        }
        {
            const int jb = ww * 16 + lq * 4;
            float bias[4];
#pragma unroll
            for (int r = 0; r < 4; r++) bias[r] = b1[jc * 128 + jb + r];
#pragma unroll
            for (int nt = 0; nt < 16; nt++) {
                const int wg = nt * 16 + lm;
                float hv[4];
#pragma unroll
                for (int r = 0; r < 4; r++) {
                    float x = acc2[nt][r] + bias[r];
                    hv[r] = x / (1.f + __expf(-x));     // silu
                }
                u32x2 pk;
                pk[0] = pack2_bf(hv[0], hv[1]);
                pk[1] = pack2_bf(hv[2], hv[3]);
                *(u32x2*)(&buf2[wg * PIT + jb]) = pk;
            }
        }
        __syncthreads();
#pragma unroll
        for (int kk = 0; kk < 4; kk++) {
            s16x8 a = *(const s16x8*)(w2_bf + (size_t)(ww * 16 + lm) * 256 + jc * 128 + kk * 32 + lq * 8);
#pragma unroll
            for (int nt = 0; nt < 16; nt++) {
                s16x8 bfv = *(const s16x8*)(&buf2[(nt * 16 + lm) * PIT + kk * 32 + lq * 8]);
                acc3[nt] = __builtin_amdgcn_mfma_f32_16x16x32_bf16(a, bfv, acc3[nt], 0, 0, 0);
            }
        }
        __syncthreads();
    }

    // ---- P8: store y = xn + b2 + ffn ----
    {
        const int ob = ww * 16 + lq * 4;
        float b2v[4];
#pragma unroll
        for (int r = 0; r < 4; r++) b2v[r] = b2[ob + r];
#pragma unroll
        for (int nt = 0; nt < 16; nt++) {
            const int wg = nt * 16 + lm;
            u32x2 d = *(const u32x2*)(&buf1[wg * PIT + ob]);
            f32x2 xa = bf2_lohi(d[0]), xb = bf2_lohi(d[1]);
            outp[(size_t)(ob + 0) * HW + hWw + wg] = xa.x + b2v[0] + acc3[nt][0];
            outp[(size_t)(ob + 1) * HW + hWw + wg] = xa.y + b2v[1] + acc3[nt][1];
            outp[(size_t)(ob + 2) * HW + hWw + wg] = xb.x + b2v[2] + acc3[nt][2];
            outp[(size_t)(ob + 3) * HW + hWw + wg] = xb.y + b2v[3] + acc3[nt][3];
        }
    }
}

// ---------------------------------------------------------------------------
extern "C" void kernel_launch(void* const* d_in, const int* in_sizes, int n_in,
                              void* d_out, int out_size, void* d_ws, size_t ws_size,
                              hipStream_t stream)
{
    const float* match_l = (const float*)d_in[0];
    const float* match_r = (const float*)d_in[1];
    const float* feat_l  = (const float*)d_in[2];
    const float* feat_r  = (const float*)d_in[3];
    const float* norm_l  = (const float*)d_in[4];
    const float* norm_r  = (const float*)d_in[5];
    const float* gml     = (const float*)d_in[6];
    const float* gmr     = (const float*)d_in[7];
    const float* cap     = (const float*)d_in[8];
    const float* gap     = (const float*)d_in[9];
    const float* wv  = (const float*)d_in[10]; const float* bv  = (const float*)d_in[11];
    const float* wn  = (const float*)d_in[12]; const float* bn  = (const float*)d_in[13];
    const float* woc = (const float*)d_in[14]; const float* boc = (const float*)d_in[15];
    const float* wog = (const float*)d_in[16]; const float* bog = (const float*)d_in[17];
    const float* wa  = (const float*)d_in[18]; const float* ba  = (const float*)d_in[19];
    const float* wo  = (const float*)d_in[20]; const float* bo  = (const float*)d_in[21];
    const float* lnw = (const float*)d_in[22]; const float* lnb = (const float*)d_in[23];
    const float* w1  = (const float*)d_in[24]; const float* b1  = (const float*)d_in[25];
    const float* w2  = (const float*)d_in[26]; const float* b2  = (const float*)d_in[27];

    float* out = (float*)d_out;
    float* out_ml  = out;
    float* out_mr  = out + (size_t)2 * CHW;
    float* ckp_out = out + (size_t)4 * CHW;
    float* gkp_out = ckp_out + (size_t)B2v * Gg * Pp * HW;

    float* ws = (float*)d_ws;
    float* bq  = ws;                       // 128 f32
    short* wbf = (short*)(bq + 128);       // 114688 bf16

    prep_kernel<<<dim3(449), dim3(256), 0, stream>>>(
        wv, woc, wog, wa, wo, w1, w2, boc, bog, ba, wbf, bq);
    mega_kernel<<<dim3(Hh, B2v), dim3(512), 0, stream>>>(
        match_l, match_r, feat_l, feat_r, norm_l, norm_r, gml, gmr, cap, gap,
        wbf, bq, bv, wn, bn, bo, lnw, lnb, b1, b2,
        out_ml, out_mr, ckp_out, gkp_out);
}